// Round 1
// baseline (4511.938 us; speedup 1.0000x reference)
//
#include <hip/hip_runtime.h>
#include <math.h>

#define E_EDGES 4096
#define N_NODES 1024
#define D_NODE 128
#define D_EDGE 256
#define HEADS 4
#define HD 64
#define N_CLASSES 16

// ---------------------------------------------------------------------------
// Generic f32 GEMM: C[M,N] = act( A@B + bias + residual )
//  - A is [M,K] row-major, OR (if nf != null) the gathered concat
//    [nf[src[row]] | nf[dst[row]]] with K = 2*D_NODE.
//  - B is [K,N] row-major. bias [N] or null. residual [M,N] or null.
//  - act: 0 = none, 1 = exact GELU (erf).
// Tile: 64x64 per block (16x16 threads, 4x4 micro-tile), K-tile 16.
// ---------------------------------------------------------------------------
__global__ __launch_bounds__(256) void gemm_f32(
    const float* __restrict__ A, const float* __restrict__ B,
    const float* __restrict__ bias, const float* __restrict__ residual,
    float* __restrict__ C, int M, int N, int K,
    const float* __restrict__ nf, const int* __restrict__ src,
    const int* __restrict__ dst, int act)
{
    __shared__ float As[64][17];
    __shared__ float Bs[16][65];
    const int tx = threadIdx.x, ty = threadIdx.y;
    const int t = ty * 16 + tx;
    const int m0 = blockIdx.y * 64, n0 = blockIdx.x * 64;
    float acc[4][4] = {};
    const int ai = t >> 2, ak = (t & 3) * 4;   // A tile: row ai, 4 cols at ak
    const int bk = t >> 4, bc = (t & 15) * 4;  // B tile: row bk, 4 cols at bc

    for (int k0 = 0; k0 < K; k0 += 16) {
        const int arow = m0 + ai;
        if (nf) {
            const int s = src[arow], d = dst[arow];
#pragma unroll
            for (int j = 0; j < 4; ++j) {
                const int kk = k0 + ak + j;
                As[ai][ak + j] = (kk < D_NODE) ? nf[s * D_NODE + kk]
                                               : nf[d * D_NODE + kk - D_NODE];
            }
        } else {
#pragma unroll
            for (int j = 0; j < 4; ++j)
                As[ai][ak + j] = A[arow * K + k0 + ak + j];
        }
#pragma unroll
        for (int j = 0; j < 4; ++j) {
            const int col = n0 + bc + j;
            Bs[bk][bc + j] = (col < N) ? B[(k0 + bk) * N + col] : 0.f;
        }
        __syncthreads();
#pragma unroll
        for (int kk = 0; kk < 16; ++kk) {
            float a[4], b[4];
#pragma unroll
            for (int i = 0; i < 4; ++i) a[i] = As[ty * 4 + i][kk];
#pragma unroll
            for (int j = 0; j < 4; ++j) b[j] = Bs[kk][tx * 4 + j];
#pragma unroll
            for (int i = 0; i < 4; ++i)
#pragma unroll
                for (int j = 0; j < 4; ++j) acc[i][j] += a[i] * b[j];
        }
        __syncthreads();
    }

#pragma unroll
    for (int i = 0; i < 4; ++i) {
        const int row = m0 + ty * 4 + i;
#pragma unroll
        for (int j = 0; j < 4; ++j) {
            const int col = n0 + tx * 4 + j;
            if (col < N) {
                float val = acc[i][j];
                if (bias) val += bias[col];
                if (residual) val += residual[row * N + col];
                if (act == 1) val = 0.5f * val * (1.f + erff(val * 0.70710678118654752f));
                C[row * N + col] = val;
            }
        }
    }
}

// ---------------------------------------------------------------------------
// Masked flash attention over edges, one (q-tile of 32, head) per block.
// scores[e,f] = dot(q[e,h,:],k[f,h,:])/8 masked by shared-endpoint adjacency,
// online softmax over f (KV tiles of 64 staged in LDS), out = attn @ v.
// q/k/v/out all [E, 256] row-major with column = h*64 + d.
// ---------------------------------------------------------------------------
#define QT 32
#define FT 64

__global__ __launch_bounds__(256) void attn_f32(
    const float* __restrict__ q, const float* __restrict__ k,
    const float* __restrict__ v, const int* __restrict__ src,
    const int* __restrict__ dst, float* __restrict__ out)
{
    __shared__ float qs[QT][HD + 1];
    __shared__ float ks[FT][HD + 1];
    __shared__ float vs[FT][HD + 1];
    __shared__ float ps[QT][FT + 1];
    __shared__ int qsrc[QT], qdst[QT], fsrc[FT], fdst[FT];
    __shared__ float mrow[QT], lrow[QT], arow_[QT];

    const int t = threadIdx.x;
    const int qb = blockIdx.x * QT;
    const int h = blockIdx.y;

    for (int i = t; i < QT * HD; i += 256) {
        const int r = i / HD, d = i % HD;
        qs[r][d] = q[(qb + r) * D_EDGE + h * HD + d];
    }
    if (t < QT) {
        qsrc[t] = src[qb + t];
        qdst[t] = dst[qb + t];
        mrow[t] = -1e30f;
        lrow[t] = 0.f;
    }

    const int r = t >> 3, g = t & 7;  // thread owns q-row r, dims g*8..g*8+7
    float acc[8] = {};

    for (int f0 = 0; f0 < E_EDGES; f0 += FT) {
        __syncthreads();  // previous tile's consumers done before overwrite
        for (int i = t; i < FT * HD; i += 256) {
            const int f = i / HD, d = i % HD;
            ks[f][d] = k[(f0 + f) * D_EDGE + h * HD + d];
            vs[f][d] = v[(f0 + f) * D_EDGE + h * HD + d];
        }
        if (t < FT) { fsrc[t] = src[f0 + t]; fdst[t] = dst[f0 + t]; }
        __syncthreads();

        // Phase A: raw scores (scaled + masked) -> ps
        const int qsr = qsrc[r], qdr = qdst[r];
#pragma unroll
        for (int jj = 0; jj < 8; ++jj) {
            const int f = g + jj * 8;
            float s = 0.f;
#pragma unroll
            for (int d = 0; d < HD; ++d) s += qs[r][d] * ks[f][d];
            const int fs = fsrc[f], fd = fdst[f];
            const bool adj = (qsr == fs) | (qsr == fd) | (qdr == fs) | (qdr == fd);
            ps[r][f] = adj ? s * 0.125f : -1e9f;
        }
        __syncthreads();

        // Phase B: per-row online-softmax update (one thread per q-row)
        if (t < QT) {
            const float mold = mrow[t];
            float tmax = mold;
            for (int f = 0; f < FT; ++f) tmax = fmaxf(tmax, ps[t][f]);
            const float alpha = expf(mold - tmax);
            float tsum = 0.f;
            for (int f = 0; f < FT; ++f) {
                const float p = expf(ps[t][f] - tmax);
                ps[t][f] = p;
                tsum += p;
            }
            lrow[t] = lrow[t] * alpha + tsum;
            mrow[t] = tmax;
            arow_[t] = alpha;
        }
        __syncthreads();

        // Phase C: rescale accumulator, add P@V for this tile
        const float alpha = arow_[r];
#pragma unroll
        for (int j = 0; j < 8; ++j) acc[j] *= alpha;
        for (int f = 0; f < FT; ++f) {
            const float p = ps[r][f];
#pragma unroll
            for (int j = 0; j < 8; ++j) acc[j] += p * vs[f][g * 8 + j];
        }
    }

    const float inv_l = 1.f / lrow[r];
#pragma unroll
    for (int j = 0; j < 8; ++j)
        out[(qb + r) * D_EDGE + h * HD + g * 8 + j] = acc[j] * inv_l;
}

// ---------------------------------------------------------------------------
extern "C" void kernel_launch(void* const* d_in, const int* in_sizes, int n_in,
                              void* d_out, int out_size, void* d_ws, size_t ws_size,
                              hipStream_t stream)
{
    const float* nf = (const float*)d_in[0];
    const float* ef = (const float*)d_in[1];
    const int* ei = (const int*)d_in[2];
    const int* src = ei;
    const int* dst = ei + E_EDGES;

    // a1: 3..12, a2: 13..22, cls: 23..26 (Wn,bn,Wq,bq,Wk,bk,Wv,bv,Wo,bo)
    const float* a_Wn[2] = {(const float*)d_in[3],  (const float*)d_in[13]};
    const float* a_bn[2] = {(const float*)d_in[4],  (const float*)d_in[14]};
    const float* a_Wq[2] = {(const float*)d_in[5],  (const float*)d_in[15]};
    const float* a_bq[2] = {(const float*)d_in[6],  (const float*)d_in[16]};
    const float* a_Wk[2] = {(const float*)d_in[7],  (const float*)d_in[17]};
    const float* a_bk[2] = {(const float*)d_in[8],  (const float*)d_in[18]};
    const float* a_Wv[2] = {(const float*)d_in[9],  (const float*)d_in[19]};
    const float* a_bv[2] = {(const float*)d_in[10], (const float*)d_in[20]};
    const float* a_Wo[2] = {(const float*)d_in[11], (const float*)d_in[21]};
    const float* a_bo[2] = {(const float*)d_in[12], (const float*)d_in[22]};
    const float* cls_W1 = (const float*)d_in[23];
    const float* cls_b1 = (const float*)d_in[24];
    const float* cls_W2 = (const float*)d_in[25];
    const float* cls_b2 = (const float*)d_in[26];

    const size_t buf = (size_t)E_EDGES * D_EDGE;  // 1M floats = 4MB
    float* ws = (float*)d_ws;
    float* x  = ws + 0 * buf;
    float* qb = ws + 1 * buf;
    float* kb = ws + 2 * buf;
    float* vb = ws + 3 * buf;
    float* ao = ws + 4 * buf;
    float* y  = ws + 5 * buf;
    float* hb = ws + 6 * buf;  // total 28MB of workspace

    const dim3 blk(16, 16);
    const dim3 gFull(D_EDGE / 64, E_EDGES / 64);   // (4, 64)
    const dim3 gCls(1, E_EDGES / 64);              // N=16
    const dim3 gAttn(E_EDGES / QT, HEADS);         // (128, 4)

    const float* ef_in = ef;
    for (int L = 0; L < 2; ++L) {
        // x = ef_in + concat(nf[src], nf[dst]) @ Wn + bn
        gemm_f32<<<gFull, blk, 0, stream>>>(nullptr, a_Wn[L], a_bn[L], ef_in, x,
                                            E_EDGES, D_EDGE, 2 * D_NODE,
                                            nf, src, dst, 0);
        // q/k/v = x @ W + b
        gemm_f32<<<gFull, blk, 0, stream>>>(x, a_Wq[L], a_bq[L], nullptr, qb,
                                            E_EDGES, D_EDGE, D_EDGE,
                                            nullptr, nullptr, nullptr, 0);
        gemm_f32<<<gFull, blk, 0, stream>>>(x, a_Wk[L], a_bk[L], nullptr, kb,
                                            E_EDGES, D_EDGE, D_EDGE,
                                            nullptr, nullptr, nullptr, 0);
        gemm_f32<<<gFull, blk, 0, stream>>>(x, a_Wv[L], a_bv[L], nullptr, vb,
                                            E_EDGES, D_EDGE, D_EDGE,
                                            nullptr, nullptr, nullptr, 0);
        // masked attention
        attn_f32<<<gAttn, 256, 0, stream>>>(qb, kb, vb, src, dst, ao);
        // y = x + ao @ Wo + bo
        gemm_f32<<<gFull, blk, 0, stream>>>(ao, a_Wo[L], a_bo[L], x, y,
                                            E_EDGES, D_EDGE, D_EDGE,
                                            nullptr, nullptr, nullptr, 0);
        ef_in = y;  // layer 2 consumes layer 1 output
    }

    // classifier: h = gelu(y @ W1 + b1); out = h @ W2 + b2
    gemm_f32<<<gFull, blk, 0, stream>>>(y, cls_W1, cls_b1, nullptr, hb,
                                        E_EDGES, D_EDGE, D_EDGE,
                                        nullptr, nullptr, nullptr, 1);
    gemm_f32<<<gCls, blk, 0, stream>>>(hb, cls_W2, cls_b2, nullptr, (float*)d_out,
                                       E_EDGES, N_CLASSES, D_EDGE,
                                       nullptr, nullptr, nullptr, 0);
}

// Round 2
// 492.454 us; speedup vs baseline: 9.1621x; 9.1621x over previous
//
#include <hip/hip_runtime.h>
#include <math.h>

#define E_EDGES 4096
#define N_NODES 1024
#define D_NODE 128
#define D_EDGE 256
#define HEADS 4
#define HD 64
#define N_CLASSES 16

// ---------------------------------------------------------------------------
// Generic f32 GEMM: C[M,N] = act( A@B + bias + residual )
//  - A is [M,K] row-major, OR (if nf != null) the gathered concat
//    [nf[src[row]] | nf[dst[row]]] with K = 2*D_NODE.
//  - B is [K,N] row-major. bias [N] or null. residual [M,N] or null.
//  - act: 0 = none, 1 = exact GELU (erf).
// Tile: 64x64 per block (16x16 threads, 4x4 micro-tile), K-tile 16.
// ---------------------------------------------------------------------------
__global__ __launch_bounds__(256) void gemm_f32(
    const float* __restrict__ A, const float* __restrict__ B,
    const float* __restrict__ bias, const float* __restrict__ residual,
    float* __restrict__ C, int M, int N, int K,
    const float* __restrict__ nf, const int* __restrict__ src,
    const int* __restrict__ dst, int act)
{
    __shared__ float As[64][17];
    __shared__ float Bs[16][65];
    const int tx = threadIdx.x, ty = threadIdx.y;
    const int t = ty * 16 + tx;
    const int m0 = blockIdx.y * 64, n0 = blockIdx.x * 64;
    float acc[4][4] = {};
    const int ai = t >> 2, ak = (t & 3) * 4;   // A tile: row ai, 4 cols at ak
    const int bk = t >> 4, bc = (t & 15) * 4;  // B tile: row bk, 4 cols at bc

    for (int k0 = 0; k0 < K; k0 += 16) {
        const int arow = m0 + ai;
        if (nf) {
            const int s = src[arow], d = dst[arow];
#pragma unroll
            for (int j = 0; j < 4; ++j) {
                const int kk = k0 + ak + j;
                As[ai][ak + j] = (kk < D_NODE) ? nf[s * D_NODE + kk]
                                               : nf[d * D_NODE + kk - D_NODE];
            }
        } else {
#pragma unroll
            for (int j = 0; j < 4; ++j)
                As[ai][ak + j] = A[arow * K + k0 + ak + j];
        }
#pragma unroll
        for (int j = 0; j < 4; ++j) {
            const int col = n0 + bc + j;
            Bs[bk][bc + j] = (col < N) ? B[(k0 + bk) * N + col] : 0.f;
        }
        __syncthreads();
#pragma unroll
        for (int kk = 0; kk < 16; ++kk) {
            float a[4], b[4];
#pragma unroll
            for (int i = 0; i < 4; ++i) a[i] = As[ty * 4 + i][kk];
#pragma unroll
            for (int j = 0; j < 4; ++j) b[j] = Bs[kk][tx * 4 + j];
#pragma unroll
            for (int i = 0; i < 4; ++i)
#pragma unroll
                for (int j = 0; j < 4; ++j) acc[i][j] += a[i] * b[j];
        }
        __syncthreads();
    }

#pragma unroll
    for (int i = 0; i < 4; ++i) {
        const int row = m0 + ty * 4 + i;
#pragma unroll
        for (int j = 0; j < 4; ++j) {
            const int col = n0 + tx * 4 + j;
            if (col < N) {
                float val = acc[i][j];
                if (bias) val += bias[col];
                if (residual) val += residual[row * N + col];
                if (act == 1) val = 0.5f * val * (1.f + erff(val * 0.70710678118654752f));
                C[row * N + col] = val;
            }
        }
    }
}

// ---------------------------------------------------------------------------
// Sparse masked attention. Key fact: adjacency density ~0.4% (avg ~16
// adjacent edges of 4096). Reference masks with -1e9, and expf(-1e9 - max)
// underflows to exactly 0 in f32, so softmax over ONLY the adjacent set is
// semantically identical.
//
// One block (256 thr = 4 waves) per query edge e:
//   Phase 1: wave 0 scans all E edges in 64-lane chunks, ballot-compacts
//            the adjacent edge ids into LDS in deterministic (ascending) order.
//   Phase 2: wave h = head h. Lane owns dim d. One-pass online softmax over
//            the ~16 candidates: coalesced k/v row loads, __shfl_xor dot
//            reduce, rescale accumulator in registers. No LDS score matrix.
// ---------------------------------------------------------------------------
#define CAND_CAP 1024

__global__ __launch_bounds__(256) void attn_sparse(
    const float* __restrict__ q, const float* __restrict__ k,
    const float* __restrict__ v, const int* __restrict__ src,
    const int* __restrict__ dst, float* __restrict__ out)
{
    __shared__ int cand[CAND_CAP];
    __shared__ int mcount;

    const int e = blockIdx.x;
    const int t = threadIdx.x;
    const int h = t >> 6, lane = t & 63;
    const int a = src[e], b = dst[e];

    // this thread's q element: head h, dim = lane
    const float qd = q[e * D_EDGE + h * HD + lane];

    if (t < 64) {  // wave 0: ordered compaction of the adjacency row
        int base = 0;
        for (int c0 = 0; c0 < E_EDGES; c0 += 64) {
            const int f = c0 + lane;
            const int sf = src[f], df = dst[f];
            const bool adj = (sf == a) | (sf == b) | (df == a) | (df == b);
            const unsigned long long mask = __ballot(adj);
            if (adj) {
                const int pos = base + __popcll(mask & ((1ull << lane) - 1ull));
                if (pos < CAND_CAP) cand[pos] = f;
            }
            base += __popcll(mask);
        }
        if (lane == 0) mcount = (base < CAND_CAP) ? base : CAND_CAP;
    }
    __syncthreads();
    const int m = mcount;

    // one-pass online softmax over candidates (>=1: e is adjacent to itself)
    float M = -1e30f, L = 0.f, O = 0.f;
    for (int i = 0; i < m; ++i) {
        const int f = cand[i];
        const float kd = k[f * D_EDGE + h * HD + lane];
        const float vd = v[f * D_EDGE + h * HD + lane];
        float s = qd * kd;
#pragma unroll
        for (int off = 32; off; off >>= 1) s += __shfl_xor(s, off);
        s *= 0.125f;  // 1/sqrt(64)
        const float Mn = fmaxf(M, s);
        const float alpha = __expf(M - Mn);  // first iter: expf(-1e30)=0
        const float p = __expf(s - Mn);
        O = O * alpha + p * vd;
        L = L * alpha + p;
        M = Mn;
    }
    out[e * D_EDGE + h * HD + lane] = O / L;
}

// ---------------------------------------------------------------------------
extern "C" void kernel_launch(void* const* d_in, const int* in_sizes, int n_in,
                              void* d_out, int out_size, void* d_ws, size_t ws_size,
                              hipStream_t stream)
{
    const float* nf = (const float*)d_in[0];
    const float* ef = (const float*)d_in[1];
    const int* ei = (const int*)d_in[2];
    const int* src = ei;
    const int* dst = ei + E_EDGES;

    // a1: 3..12, a2: 13..22, cls: 23..26 (Wn,bn,Wq,bq,Wk,bk,Wv,bv,Wo,bo)
    const float* a_Wn[2] = {(const float*)d_in[3],  (const float*)d_in[13]};
    const float* a_bn[2] = {(const float*)d_in[4],  (const float*)d_in[14]};
    const float* a_Wq[2] = {(const float*)d_in[5],  (const float*)d_in[15]};
    const float* a_bq[2] = {(const float*)d_in[6],  (const float*)d_in[16]};
    const float* a_Wk[2] = {(const float*)d_in[7],  (const float*)d_in[17]};
    const float* a_bk[2] = {(const float*)d_in[8],  (const float*)d_in[18]};
    const float* a_Wv[2] = {(const float*)d_in[9],  (const float*)d_in[19]};
    const float* a_bv[2] = {(const float*)d_in[10], (const float*)d_in[20]};
    const float* a_Wo[2] = {(const float*)d_in[11], (const float*)d_in[21]};
    const float* a_bo[2] = {(const float*)d_in[12], (const float*)d_in[22]};
    const float* cls_W1 = (const float*)d_in[23];
    const float* cls_b1 = (const float*)d_in[24];
    const float* cls_W2 = (const float*)d_in[25];
    const float* cls_b2 = (const float*)d_in[26];

    const size_t buf = (size_t)E_EDGES * D_EDGE;  // 1M floats = 4MB
    float* ws = (float*)d_ws;
    float* x  = ws + 0 * buf;
    float* qb = ws + 1 * buf;
    float* kb = ws + 2 * buf;
    float* vb = ws + 3 * buf;
    float* ao = ws + 4 * buf;
    float* y  = ws + 5 * buf;
    float* hb = ws + 6 * buf;  // total 28MB of workspace

    const dim3 blk(16, 16);
    const dim3 gFull(D_EDGE / 64, E_EDGES / 64);   // (4, 64)
    const dim3 gCls(1, E_EDGES / 64);              // N=16

    const float* ef_in = ef;
    for (int L = 0; L < 2; ++L) {
        // x = ef_in + concat(nf[src], nf[dst]) @ Wn + bn
        gemm_f32<<<gFull, blk, 0, stream>>>(nullptr, a_Wn[L], a_bn[L], ef_in, x,
                                            E_EDGES, D_EDGE, 2 * D_NODE,
                                            nf, src, dst, 0);
        // q/k/v = x @ W + b
        gemm_f32<<<gFull, blk, 0, stream>>>(x, a_Wq[L], a_bq[L], nullptr, qb,
                                            E_EDGES, D_EDGE, D_EDGE,
                                            nullptr, nullptr, nullptr, 0);
        gemm_f32<<<gFull, blk, 0, stream>>>(x, a_Wk[L], a_bk[L], nullptr, kb,
                                            E_EDGES, D_EDGE, D_EDGE,
                                            nullptr, nullptr, nullptr, 0);
        gemm_f32<<<gFull, blk, 0, stream>>>(x, a_Wv[L], a_bv[L], nullptr, vb,
                                            E_EDGES, D_EDGE, D_EDGE,
                                            nullptr, nullptr, nullptr, 0);
        // sparse masked attention
        attn_sparse<<<E_EDGES, 256, 0, stream>>>(qb, kb, vb, src, dst, ao);
        // y = x + ao @ Wo + bo
        gemm_f32<<<gFull, blk, 0, stream>>>(ao, a_Wo[L], a_bo[L], x, y,
                                            E_EDGES, D_EDGE, D_EDGE,
                                            nullptr, nullptr, nullptr, 0);
        ef_in = y;  // layer 2 consumes layer 1 output
    }

    // classifier: h = gelu(y @ W1 + b1); out = h @ W2 + b2
    gemm_f32<<<gFull, blk, 0, stream>>>(y, cls_W1, cls_b1, nullptr, hb,
                                        E_EDGES, D_EDGE, D_EDGE,
                                        nullptr, nullptr, nullptr, 1);
    gemm_f32<<<gCls, blk, 0, stream>>>(hb, cls_W2, cls_b2, nullptr, (float*)d_out,
                                       E_EDGES, N_CLASSES, D_EDGE,
                                       nullptr, nullptr, nullptr, 0);
}

// Round 3
// 301.597 us; speedup vs baseline: 14.9602x; 1.6328x over previous
//
#include <hip/hip_runtime.h>
#include <math.h>

#define E_EDGES 4096
#define N_NODES 1024
#define D_NODE 128
#define D_EDGE 256
#define HEADS 4
#define HD 64
#define N_CLASSES 16
#define CAP 256   // max adjacent edges per edge (avg ~16, worst-case ~50)

// ---------------------------------------------------------------------------
// f32 GEMM: C[M,N] = act( A@B + bias + residual )
// 64x64 tile, 256 threads, K-tile 32, 4x4 micro-tile.
// A staged TRANSPOSED in LDS (pad 68 keeps float4 reads 16B-aligned) so the
// inner loop is 2x ds_read_b128 + 16 FMA per kk (8 FMA per LDS read).
// If nf != null, A row = concat(nf[src[row]], nf[dst[row]]), K = 2*D_NODE.
// act: 0 = none, 1 = exact GELU (erf).
// ---------------------------------------------------------------------------
__global__ __launch_bounds__(256) void gemm_f32v(
    const float* __restrict__ A, const float* __restrict__ B,
    const float* __restrict__ bias, const float* __restrict__ residual,
    float* __restrict__ C, int M, int N, int K,
    const float* __restrict__ nf, const int* __restrict__ src,
    const int* __restrict__ dst, int act)
{
    __shared__ float As[32][68];   // [k][m], 68 = 64 + 4 -> 16B-aligned cols
    __shared__ float Bs[32][68];   // [k][n]
    const int t = threadIdx.x;
    const int tx = t & 15, ty = t >> 4;
    const int m0 = blockIdx.y * 64, n0 = blockIdx.x * 64;
    float acc[4][4] = {};

    for (int k0 = 0; k0 < K; k0 += 32) {
        // ---- stage A (2 float4 loads/thread, transposed scalar LDS writes)
#pragma unroll
        for (int p = 0; p < 2; ++p) {
            const int idx = t + p * 256;
            const int row = idx >> 3, kc = (idx & 7) * 4;
            float4 a4;
            if (nf) {
                const int kq = k0 + kc;
                const int node = (kq < D_NODE) ? src[m0 + row] : dst[m0 + row];
                const int col = (kq < D_NODE) ? kq : kq - D_NODE;
                a4 = *(const float4*)&nf[node * D_NODE + col];
            } else {
                a4 = *(const float4*)&A[(size_t)(m0 + row) * K + k0 + kc];
            }
            As[kc + 0][row] = a4.x; As[kc + 1][row] = a4.y;
            As[kc + 2][row] = a4.z; As[kc + 3][row] = a4.w;
        }
        // ---- stage B (2 float4 loads/thread, float4 LDS writes)
#pragma unroll
        for (int p = 0; p < 2; ++p) {
            const int idx = t + p * 256;
            const int kr = idx >> 4, nc = (idx & 15) * 4;
            float4 b4 = make_float4(0.f, 0.f, 0.f, 0.f);
            if (n0 + nc < N) b4 = *(const float4*)&B[(size_t)(k0 + kr) * N + n0 + nc];
            *(float4*)&Bs[kr][nc] = b4;
        }
        __syncthreads();
        // ---- compute: 2x b128 + 16 FMA per kk
#pragma unroll
        for (int kk = 0; kk < 32; ++kk) {
            const float4 av = *(const float4*)&As[kk][ty * 4];
            const float4 bv = *(const float4*)&Bs[kk][tx * 4];
            const float a_[4] = {av.x, av.y, av.z, av.w};
            const float b_[4] = {bv.x, bv.y, bv.z, bv.w};
#pragma unroll
            for (int i = 0; i < 4; ++i)
#pragma unroll
                for (int j = 0; j < 4; ++j) acc[i][j] += a_[i] * b_[j];
        }
        __syncthreads();
    }

#pragma unroll
    for (int i = 0; i < 4; ++i) {
        const int row = m0 + ty * 4 + i;
        const int col = n0 + tx * 4;
        if (col < N) {
            float4 r = make_float4(acc[i][0], acc[i][1], acc[i][2], acc[i][3]);
            if (bias) {
                const float4 bb = *(const float4*)&bias[col];
                r.x += bb.x; r.y += bb.y; r.z += bb.z; r.w += bb.w;
            }
            if (residual) {
                const float4 rr = *(const float4*)&residual[(size_t)row * N + col];
                r.x += rr.x; r.y += rr.y; r.z += rr.z; r.w += rr.w;
            }
            if (act == 1) {
                r.x = 0.5f * r.x * (1.f + erff(r.x * 0.70710678118654752f));
                r.y = 0.5f * r.y * (1.f + erff(r.y * 0.70710678118654752f));
                r.z = 0.5f * r.z * (1.f + erff(r.z * 0.70710678118654752f));
                r.w = 0.5f * r.w * (1.f + erff(r.w * 0.70710678118654752f));
            }
            *(float4*)&C[(size_t)row * N + col] = r;
        }
    }
}

// ---------------------------------------------------------------------------
// One-time adjacency build (edge_index is constant across both attn layers).
// One wave per query edge; ballot-compaction in ascending order -> CSR lists.
// ---------------------------------------------------------------------------
__global__ __launch_bounds__(256) void build_adj(
    const int* __restrict__ src, const int* __restrict__ dst,
    int* __restrict__ cand, int* __restrict__ ccount)
{
    const int w = threadIdx.x >> 6, lane = threadIdx.x & 63;
    const int e = blockIdx.x * 4 + w;
    const int a = src[e], b = dst[e];
    int* my = cand + (size_t)e * CAP;
    int base = 0;
    for (int c0 = 0; c0 < E_EDGES; c0 += 64) {
        const int f = c0 + lane;
        const int sf = src[f], df = dst[f];
        const bool adj = (sf == a) | (sf == b) | (df == a) | (df == b);
        const unsigned long long mk = __ballot(adj);
        if (adj) {
            const int pos = base + __popcll(mk & ((1ull << lane) - 1ull));
            if (pos < CAP) my[pos] = f;
        }
        base += __popcll(mk);
    }
    if (lane == 0) ccount[e] = (base < CAP) ? base : CAP;
}

// ---------------------------------------------------------------------------
// Sparse attention using prebuilt candidate lists. Block = edge, wave = head,
// lane = dim. One-pass online softmax; expf(-1e9-max) == 0 makes this
// semantically identical to the dense masked softmax.
// ---------------------------------------------------------------------------
__global__ __launch_bounds__(256) void attn_sparse2(
    const float* __restrict__ q, const float* __restrict__ k,
    const float* __restrict__ v, const int* __restrict__ cand,
    const int* __restrict__ ccount, float* __restrict__ out)
{
    __shared__ int lc[CAP];
    const int e = blockIdx.x;
    const int t = threadIdx.x, h = t >> 6, lane = t & 63;
    const int m = ccount[e];
    if (t < m) lc[t] = cand[(size_t)e * CAP + t];
    __syncthreads();

    const float qd = q[e * D_EDGE + h * HD + lane];
    float M = -1e30f, L = 0.f, O = 0.f;
    for (int i = 0; i < m; ++i) {
        const int f = lc[i];
        const float kd = k[f * D_EDGE + h * HD + lane];
        const float vd = v[f * D_EDGE + h * HD + lane];
        float s = qd * kd;
#pragma unroll
        for (int off = 32; off; off >>= 1) s += __shfl_xor(s, off);
        s *= 0.125f;  // 1/sqrt(64)
        const float Mn = fmaxf(M, s);
        const float alpha = __expf(M - Mn);
        const float p = __expf(s - Mn);
        O = O * alpha + p * vd;
        L = L * alpha + p;
        M = Mn;
    }
    out[e * D_EDGE + h * HD + lane] = O / L;
}

// ---------------------------------------------------------------------------
extern "C" void kernel_launch(void* const* d_in, const int* in_sizes, int n_in,
                              void* d_out, int out_size, void* d_ws, size_t ws_size,
                              hipStream_t stream)
{
    const float* nf = (const float*)d_in[0];
    const float* ef = (const float*)d_in[1];
    const int* ei = (const int*)d_in[2];
    const int* src = ei;
    const int* dst = ei + E_EDGES;

    const float* a_Wn[2] = {(const float*)d_in[3],  (const float*)d_in[13]};
    const float* a_bn[2] = {(const float*)d_in[4],  (const float*)d_in[14]};
    const float* a_Wq[2] = {(const float*)d_in[5],  (const float*)d_in[15]};
    const float* a_bq[2] = {(const float*)d_in[6],  (const float*)d_in[16]};
    const float* a_Wk[2] = {(const float*)d_in[7],  (const float*)d_in[17]};
    const float* a_bk[2] = {(const float*)d_in[8],  (const float*)d_in[18]};
    const float* a_Wv[2] = {(const float*)d_in[9],  (const float*)d_in[19]};
    const float* a_bv[2] = {(const float*)d_in[10], (const float*)d_in[20]};
    const float* a_Wo[2] = {(const float*)d_in[11], (const float*)d_in[21]};
    const float* a_bo[2] = {(const float*)d_in[12], (const float*)d_in[22]};
    const float* cls_W1 = (const float*)d_in[23];
    const float* cls_b1 = (const float*)d_in[24];
    const float* cls_W2 = (const float*)d_in[25];
    const float* cls_b2 = (const float*)d_in[26];

    const size_t buf = (size_t)E_EDGES * D_EDGE;  // 1M floats = 4MB
    float* ws = (float*)d_ws;
    float* x  = ws + 0 * buf;
    float* qb = ws + 1 * buf;
    float* kb = ws + 2 * buf;
    float* vb = ws + 3 * buf;
    float* ao = ws + 4 * buf;
    float* y  = ws + 5 * buf;
    float* hb = ws + 6 * buf;          // classifier scratch (used after attn)
    int* cand   = (int*)(ws + 6 * buf); // alias hb: cand dead before hb write
    int* ccount = (int*)(ws + 7 * buf); // 16KB tail

    const dim3 gFull(D_EDGE / 64, E_EDGES / 64);   // (4, 64) = 256 blocks
    const dim3 gCls(1, E_EDGES / 64);

    build_adj<<<E_EDGES / 4, 256, 0, stream>>>(src, dst, cand, ccount);

    const float* ef_in = ef;
    for (int L = 0; L < 2; ++L) {
        gemm_f32v<<<gFull, 256, 0, stream>>>(nullptr, a_Wn[L], a_bn[L], ef_in, x,
                                             E_EDGES, D_EDGE, 2 * D_NODE,
                                             nf, src, dst, 0);
        gemm_f32v<<<gFull, 256, 0, stream>>>(x, a_Wq[L], a_bq[L], nullptr, qb,
                                             E_EDGES, D_EDGE, D_EDGE,
                                             nullptr, nullptr, nullptr, 0);
        gemm_f32v<<<gFull, 256, 0, stream>>>(x, a_Wk[L], a_bk[L], nullptr, kb,
                                             E_EDGES, D_EDGE, D_EDGE,
                                             nullptr, nullptr, nullptr, 0);
        gemm_f32v<<<gFull, 256, 0, stream>>>(x, a_Wv[L], a_bv[L], nullptr, vb,
                                             E_EDGES, D_EDGE, D_EDGE,
                                             nullptr, nullptr, nullptr, 0);
        attn_sparse2<<<E_EDGES, 256, 0, stream>>>(qb, kb, vb, cand, ccount, ao);
        gemm_f32v<<<gFull, 256, 0, stream>>>(ao, a_Wo[L], a_bo[L], x, y,
                                             E_EDGES, D_EDGE, D_EDGE,
                                             nullptr, nullptr, nullptr, 0);
        ef_in = y;
    }

    gemm_f32v<<<gFull, 256, 0, stream>>>(y, cls_W1, cls_b1, nullptr, hb,
                                         E_EDGES, D_EDGE, D_EDGE,
                                         nullptr, nullptr, nullptr, 1);
    gemm_f32v<<<gCls, 256, 0, stream>>>(hb, cls_W2, cls_b2, nullptr, (float*)d_out,
                                        E_EDGES, N_CLASSES, D_EDGE,
                                        nullptr, nullptr, nullptr, 0);
}

// Round 4
// 248.033 us; speedup vs baseline: 18.1909x; 1.2160x over previous
//
#include <hip/hip_runtime.h>
#include <math.h>

#define E_EDGES 4096
#define N_NODES 1024
#define D_NODE 128
#define D_EDGE 256
#define HEADS 4
#define HD 64
#define N_CLASSES 16
#define CAP 256   // max adjacent edges per edge (avg ~16)
#define BK 32

// ---------------------------------------------------------------------------
// f32 GEMM core: C[tile] = act( A@B + bias + residual ), 64x64 tile, BK=32,
// 256 threads, 4x4 micro-tile. Reg-staged double buffering: next K-tile's
// global loads issue BEFORE the compute loop (latency hides under 1792cy of
// FMAs), LDS write after the barrier. A transposed in LDS ([k][m], pad 68
// keeps ds_read_b128 16B-aligned); inner kk = 2x b128 + 16 FMA.
// If nf != null: A row m = concat(nf[src[m]], nf[dst[m]]), K = 2*D_NODE.
// act: 1 = exact GELU.
// ---------------------------------------------------------------------------
__device__ __forceinline__ void gemm_core(
    const float* __restrict__ A, const float* __restrict__ B,
    const float* __restrict__ bias, const float* __restrict__ residual,
    float* __restrict__ C, int N, int K, int m0, int n0,
    const float* __restrict__ nf, const int* __restrict__ src,
    const int* __restrict__ dst, int act)
{
    __shared__ float As[BK][68];   // [k][m]
    __shared__ float Bs[BK][68];   // [k][n]
    const int t = threadIdx.x;
    const int tx = t & 15, ty = t >> 4;
    const int ar0 = t >> 3, ak0 = (t & 7) * 4;   // A: rows ar0 / ar0+32, k-col ak0
    const int br0 = t >> 4, nc = (t & 15) * 4;   // B: rows br0 / br0+16, n-col nc

    // nf-path: per-thread endpoint node ids are k-invariant -> hoist
    int sA0 = 0, dA0 = 0, sA1 = 0, dA1 = 0;
    if (nf) {
        sA0 = src[m0 + ar0];      dA0 = dst[m0 + ar0];
        sA1 = src[m0 + ar0 + 32]; dA1 = dst[m0 + ar0 + 32];
    }

    float acc[4][4] = {};
    float4 a0, a1, b0, b1, na0, na1, nb0, nb1;
    const float4 f4z = make_float4(0.f, 0.f, 0.f, 0.f);

#define LOADA(k0, r0, r1)                                                      \
    do {                                                                       \
        const int kq = (k0) + ak0;                                             \
        if (nf) {                                                              \
            const float* p0 = (kq < D_NODE) ? &nf[sA0 * D_NODE + kq]           \
                                            : &nf[dA0 * D_NODE + kq - D_NODE]; \
            const float* p1 = (kq < D_NODE) ? &nf[sA1 * D_NODE + kq]           \
                                            : &nf[dA1 * D_NODE + kq - D_NODE]; \
            r0 = *(const float4*)p0; r1 = *(const float4*)p1;                   \
        } else {                                                               \
            r0 = *(const float4*)&A[(size_t)(m0 + ar0) * K + kq];              \
            r1 = *(const float4*)&A[(size_t)(m0 + ar0 + 32) * K + kq];         \
        }                                                                      \
    } while (0)
#define LOADB(k0, r0, r1)                                                      \
    do {                                                                       \
        if (n0 + nc < N) {                                                     \
            r0 = *(const float4*)&B[(size_t)((k0) + br0) * N + n0 + nc];       \
            r1 = *(const float4*)&B[(size_t)((k0) + br0 + 16) * N + n0 + nc];  \
        } else { r0 = f4z; r1 = f4z; }                                         \
    } while (0)
#define STORELDS(x0, x1, y0, y1)                                               \
    do {                                                                       \
        As[ak0 + 0][ar0] = x0.x; As[ak0 + 1][ar0] = x0.y;                      \
        As[ak0 + 2][ar0] = x0.z; As[ak0 + 3][ar0] = x0.w;                      \
        As[ak0 + 0][ar0 + 32] = x1.x; As[ak0 + 1][ar0 + 32] = x1.y;            \
        As[ak0 + 2][ar0 + 32] = x1.z; As[ak0 + 3][ar0 + 32] = x1.w;            \
        *(float4*)&Bs[br0][nc] = y0; *(float4*)&Bs[br0 + 16][nc] = y1;         \
    } while (0)

    const int KT = K / BK;
    LOADA(0, a0, a1);
    LOADB(0, b0, b1);
    STORELDS(a0, a1, b0, b1);
    __syncthreads();

    for (int kt = 0; kt < KT; ++kt) {
        if (kt + 1 < KT) {  // issue next tile's loads before compute
            LOADA((kt + 1) * BK, na0, na1);
            LOADB((kt + 1) * BK, nb0, nb1);
        }
#pragma unroll
        for (int kk = 0; kk < BK; ++kk) {
            const float4 av = *(const float4*)&As[kk][ty * 4];
            const float4 bv = *(const float4*)&Bs[kk][tx * 4];
            const float a_[4] = {av.x, av.y, av.z, av.w};
            const float b_[4] = {bv.x, bv.y, bv.z, bv.w};
#pragma unroll
            for (int i = 0; i < 4; ++i)
#pragma unroll
                for (int j = 0; j < 4; ++j) acc[i][j] += a_[i] * b_[j];
        }
        __syncthreads();
        if (kt + 1 < KT) {
            STORELDS(na0, na1, nb0, nb1);
            __syncthreads();
        }
    }

#pragma unroll
    for (int i = 0; i < 4; ++i) {
        const int row = m0 + ty * 4 + i;
        const int col = n0 + tx * 4;
        if (col < N) {
            float4 r = make_float4(acc[i][0], acc[i][1], acc[i][2], acc[i][3]);
            if (bias) {
                const float4 bb = *(const float4*)&bias[col];
                r.x += bb.x; r.y += bb.y; r.z += bb.z; r.w += bb.w;
            }
            if (residual) {
                const float4 rr = *(const float4*)&residual[(size_t)row * N + col];
                r.x += rr.x; r.y += rr.y; r.z += rr.z; r.w += rr.w;
            }
            if (act == 1) {
                r.x = 0.5f * r.x * (1.f + erff(r.x * 0.70710678118654752f));
                r.y = 0.5f * r.y * (1.f + erff(r.y * 0.70710678118654752f));
                r.z = 0.5f * r.z * (1.f + erff(r.z * 0.70710678118654752f));
                r.w = 0.5f * r.w * (1.f + erff(r.w * 0.70710678118654752f));
            }
            *(float4*)&C[(size_t)row * N + col] = r;
        }
    }
#undef LOADA
#undef LOADB
#undef STORELDS
}

__global__ __launch_bounds__(256) void gemm_f32v(
    const float* __restrict__ A, const float* __restrict__ B,
    const float* __restrict__ bias, const float* __restrict__ residual,
    float* __restrict__ C, int N, int K,
    const float* __restrict__ nf, const int* __restrict__ src,
    const int* __restrict__ dst, int act)
{
    gemm_core(A, B, bias, residual, C, N, K,
              blockIdx.y * 64, blockIdx.x * 64, nf, src, dst, act);
}

// q/k/v fused: grid (12, 64); blockIdx.x>>2 selects matrix, &3 selects n-tile.
// 768 blocks = 3 blocks/CU -> inter-block TLP hides staging latency.
__global__ __launch_bounds__(256) void gemm_qkv(
    const float* __restrict__ x,
    const float* __restrict__ Wq, const float* __restrict__ bq,
    const float* __restrict__ Wk, const float* __restrict__ bk,
    const float* __restrict__ Wv, const float* __restrict__ bv,
    float* __restrict__ qb, float* __restrict__ kb, float* __restrict__ vb)
{
    const int wsel = blockIdx.x >> 2, nt = blockIdx.x & 3;
    const float* B = (wsel == 0) ? Wq : (wsel == 1) ? Wk : Wv;
    const float* bias = (wsel == 0) ? bq : (wsel == 1) ? bk : bv;
    float* C = (wsel == 0) ? qb : (wsel == 1) ? kb : vb;
    gemm_core(x, B, bias, nullptr, C, D_EDGE, D_EDGE,
              blockIdx.y * 64, nt * 64, nullptr, nullptr, nullptr, 0);
}

// ---------------------------------------------------------------------------
// One-time adjacency build (edge_index constant across both layers).
// Wave per query edge; ballot-compaction in ascending order -> CSR lists.
// ---------------------------------------------------------------------------
__global__ __launch_bounds__(256) void build_adj(
    const int* __restrict__ src, const int* __restrict__ dst,
    int* __restrict__ cand, int* __restrict__ ccount)
{
    const int w = threadIdx.x >> 6, lane = threadIdx.x & 63;
    const int e = blockIdx.x * 4 + w;
    const int a = src[e], b = dst[e];
    int* my = cand + (size_t)e * CAP;
    int base = 0;
    for (int c0 = 0; c0 < E_EDGES; c0 += 64) {
        const int f = c0 + lane;
        const int sf = src[f], df = dst[f];
        const bool adj = (sf == a) | (sf == b) | (df == a) | (df == b);
        const unsigned long long mk = __ballot(adj);
        if (adj) {
            const int pos = base + __popcll(mk & ((1ull << lane) - 1ull));
            if (pos < CAP) my[pos] = f;
        }
        base += __popcll(mk);
    }
    if (lane == 0) ccount[e] = (base < CAP) ? base : CAP;
}

// ---------------------------------------------------------------------------
// Sparse attention from prebuilt lists. Block = edge, wave = head, lane = dim.
// One-pass online softmax (expf(-1e9-max)==0 makes sparse == dense-masked).
// 2-way unrolled candidate loop for dual shfl-reduce ILP.
// ---------------------------------------------------------------------------
__global__ __launch_bounds__(256) void attn_sparse2(
    const float* __restrict__ q, const float* __restrict__ k,
    const float* __restrict__ v, const int* __restrict__ cand,
    const int* __restrict__ ccount, float* __restrict__ out)
{
    __shared__ int lc[CAP];
    const int e = blockIdx.x;
    const int t = threadIdx.x, h = t >> 6, lane = t & 63;
    const int m = ccount[e];
    if (t < m) lc[t] = cand[(size_t)e * CAP + t];
    __syncthreads();

    const float qd = q[e * D_EDGE + h * HD + lane];
    float M = -1e30f, L = 0.f, O = 0.f;
    int i = 0;
    for (; i + 2 <= m; i += 2) {
        const int f0 = lc[i], f1 = lc[i + 1];
        const float kd0 = k[f0 * D_EDGE + h * HD + lane];
        const float vd0 = v[f0 * D_EDGE + h * HD + lane];
        const float kd1 = k[f1 * D_EDGE + h * HD + lane];
        const float vd1 = v[f1 * D_EDGE + h * HD + lane];
        float s0 = qd * kd0, s1 = qd * kd1;
#pragma unroll
        for (int off = 32; off; off >>= 1) {
            s0 += __shfl_xor(s0, off);
            s1 += __shfl_xor(s1, off);
        }
        s0 *= 0.125f; s1 *= 0.125f;
        const float Mn = fmaxf(M, fmaxf(s0, s1));
        const float alpha = __expf(M - Mn);
        const float p0 = __expf(s0 - Mn), p1 = __expf(s1 - Mn);
        O = O * alpha + p0 * vd0 + p1 * vd1;
        L = L * alpha + p0 + p1;
        M = Mn;
    }
    if (i < m) {
        const int f = lc[i];
        const float kd = k[f * D_EDGE + h * HD + lane];
        const float vd = v[f * D_EDGE + h * HD + lane];
        float s = qd * kd;
#pragma unroll
        for (int off = 32; off; off >>= 1) s += __shfl_xor(s, off);
        s *= 0.125f;
        const float Mn = fmaxf(M, s);
        const float alpha = __expf(M - Mn);
        const float p = __expf(s - Mn);
        O = O * alpha + p * vd;
        L = L * alpha + p;
        M = Mn;
    }
    out[e * D_EDGE + h * HD + lane] = O / L;
}

// ---------------------------------------------------------------------------
extern "C" void kernel_launch(void* const* d_in, const int* in_sizes, int n_in,
                              void* d_out, int out_size, void* d_ws, size_t ws_size,
                              hipStream_t stream)
{
    const float* nf = (const float*)d_in[0];
    const float* ef = (const float*)d_in[1];
    const int* ei = (const int*)d_in[2];
    const int* src = ei;
    const int* dst = ei + E_EDGES;

    const float* a_Wn[2] = {(const float*)d_in[3],  (const float*)d_in[13]};
    const float* a_bn[2] = {(const float*)d_in[4],  (const float*)d_in[14]};
    const float* a_Wq[2] = {(const float*)d_in[5],  (const float*)d_in[15]};
    const float* a_bq[2] = {(const float*)d_in[6],  (const float*)d_in[16]};
    const float* a_Wk[2] = {(const float*)d_in[7],  (const float*)d_in[17]};
    const float* a_bk[2] = {(const float*)d_in[8],  (const float*)d_in[18]};
    const float* a_Wv[2] = {(const float*)d_in[9],  (const float*)d_in[19]};
    const float* a_bv[2] = {(const float*)d_in[10], (const float*)d_in[20]};
    const float* a_Wo[2] = {(const float*)d_in[11], (const float*)d_in[21]};
    const float* a_bo[2] = {(const float*)d_in[12], (const float*)d_in[22]};
    const float* cls_W1 = (const float*)d_in[23];
    const float* cls_b1 = (const float*)d_in[24];
    const float* cls_W2 = (const float*)d_in[25];
    const float* cls_b2 = (const float*)d_in[26];

    const size_t buf = (size_t)E_EDGES * D_EDGE;  // 1M floats = 4MB
    float* ws = (float*)d_ws;
    float* x  = ws + 0 * buf;
    float* qb = ws + 1 * buf;
    float* kb = ws + 2 * buf;
    float* vb = ws + 3 * buf;
    float* ao = ws + 4 * buf;
    float* y  = ws + 5 * buf;
    float* hb = ws + 6 * buf;           // classifier scratch (post-attn)
    int* cand   = (int*)(ws + 6 * buf); // alias hb: cand dead before hb write
    int* ccount = (int*)(ws + 7 * buf);

    const dim3 gFull(D_EDGE / 64, E_EDGES / 64);   // (4, 64)
    const dim3 gQkv(12, E_EDGES / 64);             // (12, 64) = 768 blocks
    const dim3 gCls(1, E_EDGES / 64);

    build_adj<<<E_EDGES / 4, 256, 0, stream>>>(src, dst, cand, ccount);

    const float* ef_in = ef;
    for (int L = 0; L < 2; ++L) {
        gemm_f32v<<<gFull, 256, 0, stream>>>(nullptr, a_Wn[L], a_bn[L], ef_in, x,
                                             D_EDGE, 2 * D_NODE, nf, src, dst, 0);
        gemm_qkv<<<gQkv, 256, 0, stream>>>(x, a_Wq[L], a_bq[L], a_Wk[L], a_bk[L],
                                           a_Wv[L], a_bv[L], qb, kb, vb);
        attn_sparse2<<<E_EDGES, 256, 0, stream>>>(qb, kb, vb, cand, ccount, ao);
        gemm_f32v<<<gFull, 256, 0, stream>>>(ao, a_Wo[L], a_bo[L], x, y,
                                             D_EDGE, D_EDGE,
                                             nullptr, nullptr, nullptr, 0);
        ef_in = y;
    }

    gemm_f32v<<<gFull, 256, 0, stream>>>(y, cls_W1, cls_b1, nullptr, hb,
                                         D_EDGE, D_EDGE,
                                         nullptr, nullptr, nullptr, 1);
    gemm_f32v<<<gCls, 256, 0, stream>>>(hb, cls_W2, cls_b2, nullptr, (float*)d_out,
                                        N_CLASSES, D_EDGE,
                                        nullptr, nullptr, nullptr, 0);
}

// Round 5
// 240.342 us; speedup vs baseline: 18.7730x; 1.0320x over previous
//
#include <hip/hip_runtime.h>
#include <math.h>

#define E_EDGES 4096
#define N_NODES 1024
#define D_NODE 128
#define D_EDGE 256
#define HEADS 4
#define HD 64
#define N_CLASSES 16
#define CAP 256   // max adjacent edges per edge (avg ~16)
#define BK 32

// direct-to-LDS 16B DMA (gfx950); LDS dest must be wave-uniform base + lane*16
__device__ __forceinline__ void gload_lds16(const float* g, float* l)
{
    auto g1 = (const __attribute__((address_space(1))) void*)g;
    auto l3 = (__attribute__((address_space(3))) void*)l;
    __builtin_amdgcn_global_load_lds(g1, l3, 16, 0, 0);
}

// XCD-aware remap: all blocks sharing an M-panel land on one XCD so the
// A/x panel is fetched into that XCD's L2 once. Requires gridDim.y % 8 == 0.
// If the id%8->XCD assumption is wrong this is just a permutation (safe).
__device__ __forceinline__ void xcd_remap(int& bx, int& by)
{
    const int nx = gridDim.x;
    const int lid = blockIdx.x + nx * blockIdx.y;
    const int g = lid & 7, s = lid >> 3;       // XCD, slot-within-XCD
    const int ppx = gridDim.y >> 3;            // panels per XCD
    by = g * ppx + s / nx;
    bx = s % nx;
}

// ---------------------------------------------------------------------------
// f32 GEMM core: C[64x64 tile] = act( A@B + bias + residual ), BK=32,
// 256 threads, 4x4 micro-tile.
// FULLN=true (N multiple of 64): B staged via global_load_lds DMA into
//   unpadded [32][64] (lane-linear), A reg-staged + transposed into padded
//   [32][68]; DOUBLE-buffered LDS, ONE __syncthreads per K-tile (barrier's
//   vmcnt(0) drain is exactly the DMA completion wait).
// FULLN=false: guarded reg-staged path (used only for N=16 classifier).
// If nf != null: A row m = concat(nf[src[m]], nf[dst[m]]), K = 2*D_NODE.
// act: 1 = exact GELU.
// ---------------------------------------------------------------------------
template <bool FULLN>
__device__ __forceinline__ void gemm_core(
    const float* __restrict__ A, const float* __restrict__ B,
    const float* __restrict__ bias, const float* __restrict__ residual,
    float* __restrict__ C, int N, int K, int m0, int n0,
    const float* __restrict__ nf, const int* __restrict__ src,
    const int* __restrict__ dst, int act)
{
    __shared__ float As[2][BK][68];   // [buf][k][m], pad 68: 16B-aligned cols
    __shared__ float Bs[2][BK][64];   // [buf][k][n], unpadded (DMA layout)
    const int t = threadIdx.x;
    const int tx = t & 15, ty = t >> 4;
    const int ar0 = t >> 3, ak0 = (t & 7) * 4;   // A: rows ar0/ar0+32, k ak0
    const int br0 = t >> 4, nc = (t & 15) * 4;   // B(guarded): rows br0/br0+16

    int sA0 = 0, dA0 = 0, sA1 = 0, dA1 = 0;
    if (nf) {
        sA0 = src[m0 + ar0];      dA0 = dst[m0 + ar0];
        sA1 = src[m0 + ar0 + 32]; dA1 = dst[m0 + ar0 + 32];
    }

    float acc[4][4] = {};
    float4 na0, na1, nb0, nb1;
    const float4 f4z = make_float4(0.f, 0.f, 0.f, 0.f);

#define LOADA(k0, r0, r1)                                                      \
    do {                                                                       \
        const int kq = (k0) + ak0;                                             \
        if (nf) {                                                              \
            const float* p0 = (kq < D_NODE) ? &nf[sA0 * D_NODE + kq]           \
                                            : &nf[dA0 * D_NODE + kq - D_NODE]; \
            const float* p1 = (kq < D_NODE) ? &nf[sA1 * D_NODE + kq]           \
                                            : &nf[dA1 * D_NODE + kq - D_NODE]; \
            r0 = *(const float4*)p0; r1 = *(const float4*)p1;                  \
        } else {                                                               \
            r0 = *(const float4*)&A[(size_t)(m0 + ar0) * K + kq];              \
            r1 = *(const float4*)&A[(size_t)(m0 + ar0 + 32) * K + kq];         \
        }                                                                      \
    } while (0)
#define STOREA(buf, x0, x1)                                                    \
    do {                                                                       \
        As[buf][ak0 + 0][ar0] = x0.x; As[buf][ak0 + 1][ar0] = x0.y;            \
        As[buf][ak0 + 2][ar0] = x0.z; As[buf][ak0 + 3][ar0] = x0.w;            \
        As[buf][ak0 + 0][ar0 + 32] = x1.x; As[buf][ak0 + 1][ar0 + 32] = x1.y;  \
        As[buf][ak0 + 2][ar0 + 32] = x1.z; As[buf][ak0 + 3][ar0 + 32] = x1.w;  \
    } while (0)
    // DMA B tile (k0..k0+31) x (n0..n0+63) into Bs[buf]; thread t covers
    // 16B at linear float offset t*4 and (t+256)*4 (lane-linear => DMA-legal).
#define DMAB(buf, k0)                                                          \
    do {                                                                       \
        gload_lds16(&B[(size_t)((k0) + (t >> 4)) * N + n0 + (t & 15) * 4],     \
                    &Bs[buf][0][0] + t * 4);                                   \
        gload_lds16(&B[(size_t)((k0) + 16 + (t >> 4)) * N + n0 + (t & 15) * 4],\
                    &Bs[buf][0][0] + (t + 256) * 4);                           \
    } while (0)
#define LOADB_G(k0, r0, r1)                                                    \
    do {                                                                       \
        if (n0 + nc < N) {                                                     \
            r0 = *(const float4*)&B[(size_t)((k0) + br0) * N + n0 + nc];       \
            r1 = *(const float4*)&B[(size_t)((k0) + br0 + 16) * N + n0 + nc];  \
        } else { r0 = f4z; r1 = f4z; }                                         \
    } while (0)
#define COMPUTE(buf)                                                           \
    do {                                                                       \
        _Pragma("unroll")                                                      \
        for (int kk = 0; kk < BK; ++kk) {                                      \
            const float4 av = *(const float4*)&As[buf][kk][ty * 4];            \
            const float4 bv = *(const float4*)&Bs[buf][kk][tx * 4];            \
            const float a_[4] = {av.x, av.y, av.z, av.w};                      \
            const float b_[4] = {bv.x, bv.y, bv.z, bv.w};                      \
            _Pragma("unroll")                                                  \
            for (int i = 0; i < 4; ++i)                                        \
                _Pragma("unroll")                                              \
                for (int j = 0; j < 4; ++j) acc[i][j] += a_[i] * b_[j];        \
        }                                                                      \
    } while (0)

    const int KT = K / BK;
    if (FULLN) {
        // prologue: stage tile 0
        LOADA(0, na0, na1);
        DMAB(0, 0);
        STOREA(0, na0, na1);
        __syncthreads();                       // drains DMA vmcnt too
        for (int kt = 0; kt < KT; ++kt) {
            const int cur = kt & 1;
            if (kt + 1 < KT) {                 // issue next tile's loads first
                DMAB(cur ^ 1, (kt + 1) * BK);
                LOADA((kt + 1) * BK, na0, na1);
            }
            COMPUTE(cur);
            if (kt + 1 < KT) STOREA(cur ^ 1, na0, na1);
            __syncthreads();                   // one barrier per K-tile
        }
    } else {
        float4 a0, a1, b0, b1;
        LOADA(0, a0, a1);
        LOADB_G(0, b0, b1);
        STOREA(0, a0, a1);
        *(float4*)&Bs[0][br0][nc] = b0; *(float4*)&Bs[0][br0 + 16][nc] = b1;
        __syncthreads();
        for (int kt = 0; kt < KT; ++kt) {
            if (kt + 1 < KT) { LOADA((kt + 1) * BK, a0, a1); LOADB_G((kt + 1) * BK, b0, b1); }
            COMPUTE(0);
            __syncthreads();
            if (kt + 1 < KT) {
                STOREA(0, a0, a1);
                *(float4*)&Bs[0][br0][nc] = b0; *(float4*)&Bs[0][br0 + 16][nc] = b1;
                __syncthreads();
            }
        }
    }

#pragma unroll
    for (int i = 0; i < 4; ++i) {
        const int row = m0 + ty * 4 + i;
        const int col = n0 + tx * 4;
        if (FULLN || col < N) {
            float4 r = make_float4(acc[i][0], acc[i][1], acc[i][2], acc[i][3]);
            if (bias) {
                const float4 bb = *(const float4*)&bias[col];
                r.x += bb.x; r.y += bb.y; r.z += bb.z; r.w += bb.w;
            }
            if (residual) {
                const float4 rr = *(const float4*)&residual[(size_t)row * N + col];
                r.x += rr.x; r.y += rr.y; r.z += rr.z; r.w += rr.w;
            }
            if (act == 1) {
                r.x = 0.5f * r.x * (1.f + erff(r.x * 0.70710678118654752f));
                r.y = 0.5f * r.y * (1.f + erff(r.y * 0.70710678118654752f));
                r.z = 0.5f * r.z * (1.f + erff(r.z * 0.70710678118654752f));
                r.w = 0.5f * r.w * (1.f + erff(r.w * 0.70710678118654752f));
            }
            *(float4*)&C[(size_t)row * N + col] = r;
        }
    }
#undef LOADA
#undef STOREA
#undef DMAB
#undef LOADB_G
#undef COMPUTE
}

template <bool FULLN>
__global__ __launch_bounds__(256) void gemm_f32v(
    const float* __restrict__ A, const float* __restrict__ B,
    const float* __restrict__ bias, const float* __restrict__ residual,
    float* __restrict__ C, int N, int K,
    const float* __restrict__ nf, const int* __restrict__ src,
    const int* __restrict__ dst, int act)
{
    int bx = blockIdx.x, by = blockIdx.y;
    if (FULLN) xcd_remap(bx, by);   // panel-to-XCD pinning for A/x L2 reuse
    gemm_core<FULLN>(A, B, bias, residual, C, N, K,
                     by * 64, bx * 64, nf, src, dst, act);
}

// q/k/v fused: grid (12, 64); after remap, bx>>2 selects matrix, bx&3 the
// n-tile; all 12 blocks of an M-panel share one XCD -> x panel L2-resident.
__global__ __launch_bounds__(256) void gemm_qkv(
    const float* __restrict__ x,
    const float* __restrict__ Wq, const float* __restrict__ bq,
    const float* __restrict__ Wk, const float* __restrict__ bk,
    const float* __restrict__ Wv, const float* __restrict__ bv,
    float* __restrict__ qb, float* __restrict__ kb, float* __restrict__ vb)
{
    int bx = blockIdx.x, by = blockIdx.y;
    xcd_remap(bx, by);
    const int wsel = bx >> 2, nt = bx & 3;
    const float* B = (wsel == 0) ? Wq : (wsel == 1) ? Wk : Wv;
    const float* bias = (wsel == 0) ? bq : (wsel == 1) ? bk : bv;
    float* C = (wsel == 0) ? qb : (wsel == 1) ? kb : vb;
    gemm_core<true>(x, B, bias, nullptr, C, D_EDGE, D_EDGE,
                    by * 64, nt * 64, nullptr, nullptr, nullptr, 0);
}

// ---------------------------------------------------------------------------
// One-time adjacency build (edge_index constant across both layers).
// Wave per query edge; ballot-compaction in ascending order -> CSR lists.
// ---------------------------------------------------------------------------
__global__ __launch_bounds__(256) void build_adj(
    const int* __restrict__ src, const int* __restrict__ dst,
    int* __restrict__ cand, int* __restrict__ ccount)
{
    const int w = threadIdx.x >> 6, lane = threadIdx.x & 63;
    const int e = blockIdx.x * 4 + w;
    const int a = src[e], b = dst[e];
    int* my = cand + (size_t)e * CAP;
    int base = 0;
    for (int c0 = 0; c0 < E_EDGES; c0 += 64) {
        const int f = c0 + lane;
        const int sf = src[f], df = dst[f];
        const bool adj = (sf == a) | (sf == b) | (df == a) | (df == b);
        const unsigned long long mk = __ballot(adj);
        if (adj) {
            const int pos = base + __popcll(mk & ((1ull << lane) - 1ull));
            if (pos < CAP) my[pos] = f;
        }
        base += __popcll(mk);
    }
    if (lane == 0) ccount[e] = (base < CAP) ? base : CAP;
}

// ---------------------------------------------------------------------------
// Sparse attention from prebuilt lists. Block = edge, wave = head, lane = dim.
// One-pass online softmax (expf(-1e9-max)==0 makes sparse == dense-masked).
// ---------------------------------------------------------------------------
__global__ __launch_bounds__(256) void attn_sparse2(
    const float* __restrict__ q, const float* __restrict__ k,
    const float* __restrict__ v, const int* __restrict__ cand,
    const int* __restrict__ ccount, float* __restrict__ out)
{
    __shared__ int lc[CAP];
    const int e = blockIdx.x;
    const int t = threadIdx.x, h = t >> 6, lane = t & 63;
    const int m = ccount[e];
    if (t < m) lc[t] = cand[(size_t)e * CAP + t];
    __syncthreads();

    const float qd = q[e * D_EDGE + h * HD + lane];
    float M = -1e30f, L = 0.f, O = 0.f;
    int i = 0;
    for (; i + 2 <= m; i += 2) {
        const int f0 = lc[i], f1 = lc[i + 1];
        const float kd0 = k[f0 * D_EDGE + h * HD + lane];
        const float vd0 = v[f0 * D_EDGE + h * HD + lane];
        const float kd1 = k[f1 * D_EDGE + h * HD + lane];
        const float vd1 = v[f1 * D_EDGE + h * HD + lane];
        float s0 = qd * kd0, s1 = qd * kd1;
#pragma unroll
        for (int off = 32; off; off >>= 1) {
            s0 += __shfl_xor(s0, off);
            s1 += __shfl_xor(s1, off);
        }
        s0 *= 0.125f; s1 *= 0.125f;
        const float Mn = fmaxf(M, fmaxf(s0, s1));
        const float alpha = __expf(M - Mn);
        const float p0 = __expf(s0 - Mn), p1 = __expf(s1 - Mn);
        O = O * alpha + p0 * vd0 + p1 * vd1;
        L = L * alpha + p0 + p1;
        M = Mn;
    }
    if (i < m) {
        const int f = lc[i];
        const float kd = k[f * D_EDGE + h * HD + lane];
        const float vd = v[f * D_EDGE + h * HD + lane];
        float s = qd * kd;
#pragma unroll
        for (int off = 32; off; off >>= 1) s += __shfl_xor(s, off);
        s *= 0.125f;
        const float Mn = fmaxf(M, s);
        const float alpha = __expf(M - Mn);
        const float p = __expf(s - Mn);
        O = O * alpha + p * vd;
        L = L * alpha + p;
        M = Mn;
    }
    out[e * D_EDGE + h * HD + lane] = O / L;
}

// ---------------------------------------------------------------------------
extern "C" void kernel_launch(void* const* d_in, const int* in_sizes, int n_in,
                              void* d_out, int out_size, void* d_ws, size_t ws_size,
                              hipStream_t stream)
{
    const float* nf = (const float*)d_in[0];
    const float* ef = (const float*)d_in[1];
    const int* ei = (const int*)d_in[2];
    const int* src = ei;
    const int* dst = ei + E_EDGES;

    const float* a_Wn[2] = {(const float*)d_in[3],  (const float*)d_in[13]};
    const float* a_bn[2] = {(const float*)d_in[4],  (const float*)d_in[14]};
    const float* a_Wq[2] = {(const float*)d_in[5],  (const float*)d_in[15]};
    const float* a_bq[2] = {(const float*)d_in[6],  (const float*)d_in[16]};
    const float* a_Wk[2] = {(const float*)d_in[7],  (const float*)d_in[17]};
    const float* a_bk[2] = {(const float*)d_in[8],  (const float*)d_in[18]};
    const float* a_Wv[2] = {(const float*)d_in[9],  (const float*)d_in[19]};
    const float* a_bv[2] = {(const float*)d_in[10], (const float*)d_in[20]};
    const float* a_Wo[2] = {(const float*)d_in[11], (const float*)d_in[21]};
    const float* a_bo[2] = {(const float*)d_in[12], (const float*)d_in[22]};
    const float* cls_W1 = (const float*)d_in[23];
    const float* cls_b1 = (const float*)d_in[24];
    const float* cls_W2 = (const float*)d_in[25];
    const float* cls_b2 = (const float*)d_in[26];

    const size_t buf = (size_t)E_EDGES * D_EDGE;  // 1M floats = 4MB
    float* ws = (float*)d_ws;
    float* x  = ws + 0 * buf;
    float* qb = ws + 1 * buf;
    float* kb = ws + 2 * buf;
    float* vb = ws + 3 * buf;
    float* ao = ws + 4 * buf;
    float* y  = ws + 5 * buf;
    float* hb = ws + 6 * buf;           // classifier scratch (post-attn)
    int* cand   = (int*)(ws + 6 * buf); // alias hb: cand dead before hb write
    int* ccount = (int*)(ws + 7 * buf);

    const dim3 gFull(D_EDGE / 64, E_EDGES / 64);   // (4, 64)
    const dim3 gQkv(12, E_EDGES / 64);             // (12, 64) = 768 blocks
    const dim3 gCls(1, E_EDGES / 64);

    build_adj<<<E_EDGES / 4, 256, 0, stream>>>(src, dst, cand, ccount);

    const float* ef_in = ef;
    for (int L = 0; L < 2; ++L) {
        gemm_f32v<true><<<gFull, 256, 0, stream>>>(nullptr, a_Wn[L], a_bn[L], ef_in, x,
                                                   D_EDGE, 2 * D_NODE, nf, src, dst, 0);
        gemm_qkv<<<gQkv, 256, 0, stream>>>(x, a_Wq[L], a_bq[L], a_Wk[L], a_bk[L],
                                           a_Wv[L], a_bv[L], qb, kb, vb);
        attn_sparse2<<<E_EDGES, 256, 0, stream>>>(qb, kb, vb, cand, ccount, ao);
        gemm_f32v<true><<<gFull, 256, 0, stream>>>(ao, a_Wo[L], a_bo[L], x, y,
                                                   D_EDGE, D_EDGE,
                                                   nullptr, nullptr, nullptr, 0);
        ef_in = y;
    }

    gemm_f32v<true><<<gFull, 256, 0, stream>>>(y, cls_W1, cls_b1, nullptr, hb,
                                               D_EDGE, D_EDGE,
                                               nullptr, nullptr, nullptr, 1);
    gemm_f32v<false><<<gCls, 256, 0, stream>>>(hb, cls_W2, cls_b2, nullptr, (float*)d_out,
                                               N_CLASSES, D_EDGE,
                                               nullptr, nullptr, nullptr, 0);
}